// Round 2
// baseline (273.753 us; speedup 1.0000x reference)
//
#include <hip/hip_runtime.h>

// SingleStageDetector: B=256, CIN=1280, H=W=7, HID=128, OUT_DIM=65, A=9, NCLS=20, NGT=40
// DTYPE (R2): inputs/outputs are float32 per the reference. R1's NaN came from
// misreading f32 buffers as bf16 u16 pairs (mantissa half-words decode as NaN/Inf).

#define CIN_  1280
#define HW_   49
#define HID_  128
#define OUTD_ 65
#define NGT_  40
#define NP_   441

// flat output offsets (elements), in reference return order
#define CONF_OFF 0
#define OFFS_OFF 112896    // 256*9*49
#define CLS_OFF  564480    // + 256*9*4*49
#define IOU_OFF  815360    // + 256*20*49 ; total 5,331,200

__device__ __forceinline__ float sigmoidf_(float v) {
    return 1.f / (1.f + __expf(-v));
}

// ---------------------------------------------------------------------------
// Kernel 1: per-image detector head. One block (512 thr) per image.
//   h   = leaky_relu(W1 @ F[b] + b1)     (128 x 49)
//   out = W2 @ h + b2                    (65 x 49) + sigmoid epilogues
// LDS carve (65,024 B):
//   smW : f32, region 8320 floats. Per K-chunk holds W1 [128][33] (4224 used);
//         after GEMM1 re-staged with W2 [65][128] (8320, exact fit).
//   smF : f32 [32][52]  (1664)   feature K-chunk, float4 reads (52*4 % 16 == 0)
//   smH : f32 [128][49] (6272)   h intermediate
// Thread map: og = tid&31, hwg = tid>>5. o = og + 32*j (j<4) -> W-read bank
// (og*33+cc)%32 = (og+cc)%32, conflict-free. hw = hwg*4 + k (k<4), hwg<13 active.
// ---------------------------------------------------------------------------
__global__ __launch_bounds__(512) void head_kernel(
    const float* __restrict__ F,   // (256,1280,7,7)
    const float* __restrict__ W1,  // (128,1280)
    const float* __restrict__ B1,  // (128,)
    const float* __restrict__ W2,  // (65,128)
    const float* __restrict__ B2,  // (65,)
    float* __restrict__ out)
{
    __shared__ float smem[16256];           // 65,024 bytes
    float* smW = smem;                      // [128][33] per chunk / later [65][128]
    float* smF = smem + 8320;               // [32][52]
    float* smH = smem + 9984;               // [128][49]

    const int tid = threadIdx.x;
    const int b   = blockIdx.x;
    const int og  = tid & 31;
    const int hwg = tid >> 5;               // 0..15
    const int hw0 = hwg * 4;

    const float* Fb = F + b * (CIN_ * HW_);

    float acc[4][4];
    #pragma unroll
    for (int j = 0; j < 4; ++j)
        #pragma unroll
        for (int k = 0; k < 4; ++k) acc[j][k] = 0.f;

    for (int chunk = 0; chunk < 40; ++chunk) {
        const int c0 = chunk * 32;
        __syncthreads();
        // stage features chunk: 32 rows x 49 f32, coalesced
        for (int i = tid; i < 32 * 49; i += 512) {
            int c  = i / 49;
            int hw = i - c * 49;
            smF[c * 52 + hw] = Fb[c0 * 49 + i];
        }
        // stage W1 chunk: 128 o x 32 c, coalesced reads, conflict-free writes
        for (int i = tid; i < 4096; i += 512) {
            int o = i >> 5, cc = i & 31;
            smW[o * 33 + cc] = W1[o * CIN_ + c0 + cc];
        }
        __syncthreads();
        if (hwg < 13) {                      // hw0 >= 52 threads idle in compute
            #pragma unroll 8
            for (int cc = 0; cc < 32; ++cc) {
                float4 f = *(const float4*)(smF + cc * 52 + hw0);
                #pragma unroll
                for (int j = 0; j < 4; ++j) {
                    float w = smW[(og + 32 * j) * 33 + cc];
                    acc[j][0] = fmaf(w, f.x, acc[j][0]);
                    acc[j][1] = fmaf(w, f.y, acc[j][1]);
                    acc[j][2] = fmaf(w, f.z, acc[j][2]);
                    acc[j][3] = fmaf(w, f.w, acc[j][3]);
                }
            }
        }
    }

    // bias + leaky relu -> smH
    if (hwg < 13) {
        #pragma unroll
        for (int j = 0; j < 4; ++j) {
            int o = og + 32 * j;
            float bias = B1[o];
            #pragma unroll
            for (int k = 0; k < 4; ++k) {
                int hw = hw0 + k;
                if (hw < 49) {
                    float v = acc[j][k] + bias;
                    v = v > 0.f ? v : 0.01f * v;
                    smH[o * 49 + hw] = v;
                }
            }
        }
    }
    __syncthreads();   // all smW reads + smH writes done
    // stage W2 into smW region (65*128 = 8320 floats, exact fit)
    for (int i = tid; i < OUTD_ * HID_; i += 512) smW[i] = W2[i];
    __syncthreads();

    // GEMM2 + epilogue: one output element per thread-iteration (65*49 = 3185)
    for (int idx = tid; idx < OUTD_ * HW_; idx += 512) {
        int o2 = idx / 49;
        int hw = idx - o2 * 49;
        const float* wr = smW + o2 * HID_;
        const float* hc = smH + hw;
        float s0 = 0.f, s1 = 0.f, s2 = 0.f, s3 = 0.f;
        for (int k = 0; k < HID_; k += 4) {
            s0 = fmaf(wr[k + 0], hc[(k + 0) * 49], s0);
            s1 = fmaf(wr[k + 1], hc[(k + 1) * 49], s1);
            s2 = fmaf(wr[k + 2], hc[(k + 2) * 49], s2);
            s3 = fmaf(wr[k + 3], hc[(k + 3) * 49], s3);
        }
        float a = B2[o2] + ((s0 + s1) + (s2 + s3));

        unsigned int dst;
        float val;
        if (o2 < 36) {                       // offsets (B,9,4,7,7)
            int an = o2 >> 2, kk = o2 & 3;
            val = (kk < 2) ? (sigmoidf_(a) - 0.5f) : a;
            dst = OFFS_OFF + b * 1764 + an * 196 + kk * 49 + hw;
        } else if (o2 < 45) {                // conf (B,9,7,7)
            val = sigmoidf_(a);
            dst = CONF_OFF + b * 441 + (o2 - 36) * 49 + hw;
        } else {                             // class (B,20,7,7)
            val = a;
            dst = CLS_OFF + b * 980 + (o2 - 45) * 49 + hw;
        }
        out[dst] = val;
    }
}

// ---------------------------------------------------------------------------
// Kernel 2: IoU matrix (B, 441, 40). One block per image.
// P[p = a*49 + y*7 + x] = [ctr - anc/2, ctr + anc/2]; legal iff min coord > 0.
// ---------------------------------------------------------------------------
__global__ __launch_bounds__(256) void iou_kernel(
    const float* __restrict__ grid,   // (256,7,7,2)
    const float* __restrict__ bbox,   // (256,40,5)
    const float* __restrict__ anc,    // (9,2)
    float* __restrict__ out)
{
    __shared__ float smG[NGT_][4];
    __shared__ float smGA[NGT_];
    const int tid = threadIdx.x;
    const int b   = blockIdx.x;

    if (tid < NGT_) {
        float x1 = bbox[b * 200 + tid * 5 + 0];
        float y1 = bbox[b * 200 + tid * 5 + 1];
        float x2 = bbox[b * 200 + tid * 5 + 2];
        float y2 = bbox[b * 200 + tid * 5 + 3];
        smG[tid][0] = x1; smG[tid][1] = y1; smG[tid][2] = x2; smG[tid][3] = y2;
        smGA[tid] = (x2 - x1) * (y2 - y1);
    }
    __syncthreads();

    for (int p = tid; p < NP_; p += 256) {
        int a = p / 49;
        int r = p - a * 49;
        float cx = grid[b * 98 + r * 2 + 0];
        float cy = grid[b * 98 + r * 2 + 1];
        float hx = anc[a * 2 + 0] * 0.5f;
        float hy = anc[a * 2 + 1] * 0.5f;
        float px1 = cx - hx, py1 = cy - hy, px2 = cx + hx, py2 = cy + hy;
        float pa = (px2 - px1) * (py2 - py1);
        bool legal = fminf(fminf(px1, py1), fminf(px2, py2)) > 0.f;

        float buf[40] __attribute__((aligned(16)));
        #pragma unroll
        for (int g = 0; g < NGT_; ++g) {
            float tlx = fmaxf(px1, smG[g][0]);
            float tly = fmaxf(py1, smG[g][1]);
            float brx = fminf(px2, smG[g][2]);
            float bry = fminf(py2, smG[g][3]);
            float dx = brx - tlx; dx = dx > 0.f ? dx : 0.f;
            float dy = bry - tly; dy = dy > 0.f ? dy : 0.f;
            float inter = legal ? dx * dy : 0.f;
            buf[g] = inter / (smGA[g] + pa - inter);
        }
        // 160 B contiguous, 16B-aligned: 4*(815360 + 17640*b + 40*p) % 16 == 0
        float4* dst = (float4*)(out + IOU_OFF + b * 17640 + p * 40);
        const float4* src = (const float4*)buf;
        #pragma unroll
        for (int q = 0; q < 10; ++q) dst[q] = src[q];
    }
}

extern "C" void kernel_launch(void* const* d_in, const int* in_sizes, int n_in,
                              void* d_out, int out_size, void* d_ws, size_t ws_size,
                              hipStream_t stream) {
    const float* F  = (const float*)d_in[0]; // features
    const float* G  = (const float*)d_in[1]; // grid
    const float* BB = (const float*)d_in[2]; // bboxes
    const float* AN = (const float*)d_in[3]; // anc
    const float* W1 = (const float*)d_in[4];
    const float* B1 = (const float*)d_in[5];
    const float* W2 = (const float*)d_in[6];
    const float* B2 = (const float*)d_in[7];
    float* out = (float*)d_out;

    head_kernel<<<256, 512, 0, stream>>>(F, W1, B1, W2, B2, out);
    iou_kernel<<<256, 256, 0, stream>>>(G, BB, AN, out);
}

// Round 3
// 174.149 us; speedup vs baseline: 1.5719x; 1.5719x over previous
//
#include <hip/hip_runtime.h>

// SingleStageDetector fused head+IoU. B=256, CIN=1280, H=W=7, HID=128,
// OUT_DIM=65, A=9, NCLS=20, NGT=40. f32 I/O; GEMM1 via bf16 MFMA (fp32 acc).

#define CIN_  1280
#define HW_   49
#define HID_  128
#define OUTD_ 65
#define NGT_  40
#define NP_   441
#define KC    64          // channels per K-chunk
#define NCH   20          // 1280 / 64

// flat output offsets (elements), reference return order
#define CONF_OFF 0
#define OFFS_OFF 112896   // 256*9*49
#define CLS_OFF  564480   // + 256*9*4*49
#define IOU_OFF  815360   // + 256*20*49 ; total 5,331,200

typedef __bf16 bf16x8 __attribute__((ext_vector_type(8)));
typedef float  f32x4  __attribute__((ext_vector_type(4)));

__device__ __forceinline__ unsigned pack2bf(float lo, float hi) {
    unsigned a = __float_as_uint(lo);
    unsigned b = __float_as_uint(hi);
    a = (a + 0x7FFFu + ((a >> 16) & 1u)) >> 16;   // RNE f32->bf16
    b = (b + 0x7FFFu + ((b >> 16) & 1u)) >> 16;
    return a | (b << 16);
}
__device__ __forceinline__ float sigmoidf_(float v) { return 1.f / (1.f + __expf(-v)); }

__device__ __forceinline__ bf16x8 ld_frag(const unsigned* p) {
    union { uint4 u; bf16x8 v; } x;
    x.u = *(const uint4*)p;                       // 16B-aligned ds_read_b128
    return x.v;
}

// LDS carve (u32 units):
//   smA: 128 rows x 36 u32  — W1 chunk, packed bf16 [o][c], stride 36 (16B-aligned,
//        b128 frag reads hit the 8-phase minimum; staging writes conflict-free)
//   smB: 64 rows x 36 u32   — F chunk as B^T: [hw][c] packed bf16
//   smH: 128x49 f32         — h intermediate
// After GEMM1, smA region aliases smP (441*6 f32), smB aliases smG (40*5 f32).
#define SA_STRIDE 36
#define SA_SIZE   (128 * SA_STRIDE)   // 4608 u32
#define SB_SIZE   (64 * SA_STRIDE)    // 2304 u32
#define SH_SIZE   (HID_ * HW_)        // 6272 f32
// total = (4608 + 2304 + 6272) * 4 = 52,736 B

__global__ __launch_bounds__(512) void fused_kernel(
    const float* __restrict__ F,     // (256,1280,7,7)
    const float* __restrict__ grid,  // (256,7,7,2)
    const float* __restrict__ bbox,  // (256,40,5)
    const float* __restrict__ anc,   // (9,2)
    const float* __restrict__ W1,    // (128,1280)
    const float* __restrict__ B1,    // (128,)
    const float* __restrict__ W2,    // (65,128)
    const float* __restrict__ B2,    // (65,)
    float* __restrict__ out)
{
    __shared__ unsigned lds[SA_SIZE + SB_SIZE + SH_SIZE];
    unsigned* smA = lds;
    unsigned* smB = lds + SA_SIZE;
    float*    smH = (float*)(lds + SA_SIZE + SB_SIZE);
    float*    smP = (float*)lds;               // 441*6 = 2646 f32 <= 4608
    float*    smG = (float*)(lds + SA_SIZE);   // 40*5 = 200 f32 <= 2304

    const int tid  = threadIdx.x;
    const int b    = blockIdx.x;
    const int lane = tid & 63;
    const int w    = tid >> 6;     // wave 0..7 = M-tile (o-rows 16w..16w+15)
    const int quad = lane >> 4;    // 0..3
    const int m16  = lane & 15;

    const float* Fb = F + b * (CIN_ * HW_);

    f32x4 acc[4];
    #pragma unroll
    for (int nt = 0; nt < 4; ++nt) acc[nt] = (f32x4)(0.f);

    for (int ch = 0; ch < NCH; ++ch) {
        const int c0 = ch * KC;
        __syncthreads();
        // stage W1 chunk: 128 o x 32 u32-pairs; float2 reads, conflict-free writes
        #pragma unroll
        for (int rr = 0; rr < 8; ++rr) {
            int pi = tid + rr * 512;                 // 0..4095
            int o = pi >> 5, cp = pi & 31;
            float2 f = *(const float2*)(W1 + o * CIN_ + c0 + 2 * cp);
            smA[o * SA_STRIDE + cp] = pack2bf(f.x, f.y);
        }
        // stage F chunk as B^T: [hw][cpair]; coalesced f32 reads, banks (4hw+cp) distinct
        for (int pi = tid; pi < 32 * 49; pi += 512) {
            int cp = pi / 49;
            int hw = pi - cp * 49;
            const float* src = Fb + (c0 + 2 * cp) * HW_ + hw;
            smB[hw * SA_STRIDE + cp] = pack2bf(src[0], src[HW_]);
        }
        __syncthreads();
        // MFMA: A[m=lane&15][k=quad*8+j] (verified m89/m91); D row=quad*4+reg, col=lane&15
        const unsigned* Abase = smA + (w * 16 + m16) * SA_STRIDE + quad * 4;
        const unsigned* Bbase = smB + m16 * SA_STRIDE + quad * 4;
        #pragma unroll
        for (int ks = 0; ks < 2; ++ks) {
            bf16x8 af = ld_frag(Abase + ks * 16);
            #pragma unroll
            for (int nt = 0; nt < 4; ++nt) {
                bf16x8 bf = ld_frag(Bbase + nt * 16 * SA_STRIDE + ks * 16);
                acc[nt] = __builtin_amdgcn_mfma_f32_16x16x32_bf16(af, bf, acc[nt], 0, 0, 0);
            }
        }
    }

    // bias + leaky_relu -> smH[o][hw]   (D: o = 16w + quad*4 + r, hw = nt*16 + m16)
    #pragma unroll
    for (int nt = 0; nt < 4; ++nt) {
        int hw = nt * 16 + m16;
        if (hw < HW_) {
            #pragma unroll
            for (int r = 0; r < 4; ++r) {
                int o = w * 16 + quad * 4 + r;
                float v = acc[nt][r] + B1[o];
                v = v > 0.f ? v : 0.01f * v;
                smH[o * HW_ + hw] = v;
            }
        }
    }
    __syncthreads();   // smH ready; smA/smB regions free for iou staging

    // stage IoU inputs into freed LDS (concurrent with GEMM2)
    if (tid < NP_) {
        int p = tid, a = p / 49, r = p - a * 49;
        float cx = grid[b * 98 + 2 * r], cy = grid[b * 98 + 2 * r + 1];
        float hx = anc[2 * a] * 0.5f,    hy = anc[2 * a + 1] * 0.5f;
        float x1 = cx - hx, y1 = cy - hy, x2 = cx + hx, y2 = cy + hy;
        smP[p * 6 + 0] = x1; smP[p * 6 + 1] = y1;
        smP[p * 6 + 2] = x2; smP[p * 6 + 3] = y2;
        smP[p * 6 + 4] = (x2 - x1) * (y2 - y1);
        smP[p * 6 + 5] = (fminf(fminf(x1, y1), fminf(x2, y2)) > 0.f) ? 1.f : 0.f;
    }
    if (tid >= 472) {                      // 40 threads, disjoint from tid<441
        int g = tid - 472;
        float x1 = bbox[b * 200 + g * 5 + 0];
        float y1 = bbox[b * 200 + g * 5 + 1];
        float x2 = bbox[b * 200 + g * 5 + 2];
        float y2 = bbox[b * 200 + g * 5 + 3];
        smG[g * 5 + 0] = x1; smG[g * 5 + 1] = y1;
        smG[g * 5 + 2] = x2; smG[g * 5 + 3] = y2;
        smG[g * 5 + 4] = (x2 - x1) * (y2 - y1);
    }

    // GEMM2 (65x49 = W2[65][128] @ smH) + epilogue, f32 vector
    for (int idx = tid; idx < OUTD_ * HW_; idx += 512) {
        int o2 = idx / 49;
        int hw = idx - o2 * 49;
        const float4* wr = (const float4*)(W2 + o2 * HID_);
        const float*  hc = smH + hw;
        float s0 = 0.f, s1 = 0.f, s2 = 0.f, s3 = 0.f;
        #pragma unroll 8
        for (int k4 = 0; k4 < 32; ++k4) {
            float4 wv = wr[k4];
            s0 = fmaf(wv.x, hc[(4 * k4 + 0) * HW_], s0);
            s1 = fmaf(wv.y, hc[(4 * k4 + 1) * HW_], s1);
            s2 = fmaf(wv.z, hc[(4 * k4 + 2) * HW_], s2);
            s3 = fmaf(wv.w, hc[(4 * k4 + 3) * HW_], s3);
        }
        float a = B2[o2] + ((s0 + s1) + (s2 + s3));

        unsigned int dst;
        float val;
        if (o2 < 36) {                       // offsets (B,9,4,7,7)
            int an = o2 >> 2, kk = o2 & 3;
            val = (kk < 2) ? (sigmoidf_(a) - 0.5f) : a;
            dst = OFFS_OFF + b * 1764 + an * 196 + kk * 49 + hw;
        } else if (o2 < 45) {                // conf (B,9,7,7)
            val = sigmoidf_(a);
            dst = CONF_OFF + b * 441 + (o2 - 36) * 49 + hw;
        } else {                             // class (B,20,7,7)
            val = a;
            dst = CLS_OFF + b * 980 + (o2 - 45) * 49 + hw;
        }
        out[dst] = val;
    }
    __syncthreads();   // smP/smG staged, GEMM2 done

    // IoU: flat (p,g) loop, coalesced f32 stores (no per-thread array)
    for (int idx = tid; idx < NP_ * NGT_; idx += 512) {
        int p = idx / 40;
        int g = idx - p * 40;
        const float* P = smP + p * 6;
        const float* G = smG + g * 5;
        float tlx = fmaxf(P[0], G[0]);
        float tly = fmaxf(P[1], G[1]);
        float brx = fminf(P[2], G[2]);
        float bry = fminf(P[3], G[3]);
        float dx = fmaxf(brx - tlx, 0.f);
        float dy = fmaxf(bry - tly, 0.f);
        float inter = dx * dy * P[5];        // *legal
        out[IOU_OFF + b * (NP_ * NGT_) + idx] = inter / (G[4] + P[4] - inter);
    }
}

extern "C" void kernel_launch(void* const* d_in, const int* in_sizes, int n_in,
                              void* d_out, int out_size, void* d_ws, size_t ws_size,
                              hipStream_t stream) {
    const float* F  = (const float*)d_in[0];
    const float* G  = (const float*)d_in[1];
    const float* BB = (const float*)d_in[2];
    const float* AN = (const float*)d_in[3];
    const float* W1 = (const float*)d_in[4];
    const float* B1 = (const float*)d_in[5];
    const float* W2 = (const float*)d_in[6];
    const float* B2 = (const float*)d_in[7];
    float* out = (float*)d_out;

    fused_kernel<<<256, 512, 0, stream>>>(F, G, BB, AN, W1, B1, W2, B2, out);
}

// Round 4
// 149.006 us; speedup vs baseline: 1.8372x; 1.1687x over previous
//
#include <hip/hip_runtime.h>

// SingleStageDetector fused head+IoU, R4. f32 I/O; GEMM1 via bf16 MFMA.
// Pipeline: prep_w1 converts W1 -> per-chunk fragment-order XOR-swizzled bf16
// in d_ws; fused kernel stages A via global_load_lds (dbuf, 1 chunk ahead),
// F via register prefetch (1 chunk ahead), MFMA 16x16x32_bf16.

#define CIN_  1280
#define HW_   49
#define HID_  128
#define OUTD_ 65
#define NGT_  40
#define NP_   441
#define NCH   20          // 1280 / 64 channels per chunk

// flat output offsets (elements), reference return order
#define CONF_OFF 0
#define OFFS_OFF 112896   // 256*9*49
#define CLS_OFF  564480   // + 256*9*4*49
#define IOU_OFF  815360   // + 256*20*49 ; total 5,331,200

#define W1C_U32  81920    // 20 chunks * 4096 u32 in d_ws

typedef __bf16 bf16x8 __attribute__((ext_vector_type(8)));
typedef float  f32x4  __attribute__((ext_vector_type(4)));

__device__ __forceinline__ unsigned pack2bf(float lo, float hi) {
    unsigned a = __float_as_uint(lo);
    unsigned b = __float_as_uint(hi);
    a = (a + 0x7FFFu + ((a >> 16) & 1u)) >> 16;   // RNE f32->bf16
    b = (b + 0x7FFFu + ((b >> 16) & 1u)) >> 16;
    return a | (b << 16);
}
__device__ __forceinline__ float bflo(unsigned u) { return __uint_as_float(u << 16); }
__device__ __forceinline__ float bfhi(unsigned u) { return __uint_as_float(u & 0xFFFF0000u); }
__device__ __forceinline__ float sigmoidf_(float v) { return 1.f / (1.f + __expf(-v)); }

__device__ __forceinline__ bf16x8 ld_frag(const unsigned* p) {
    union { uint4 u; bf16x8 v; } x;
    x.u = *(const uint4*)p;                       // 16B-aligned ds_read_b128
    return x.v;
}
__device__ __forceinline__ void gld_lds16(const unsigned* g, unsigned* l) {
    __builtin_amdgcn_global_load_lds(
        (const __attribute__((address_space(1))) unsigned*)g,
        (__attribute__((address_space(3))) unsigned*)l, 16, 0, 0);
}

// ---------------------------------------------------------------------------
// prep_w1: W1 (128,1280) f32 -> gW1c: per chunk ch, 128 rows x 32 u32 packed
// bf16 pairs, with in-row 16B-block swizzle phys_blk = blk ^ (o&7).
// Chunk image is LDS-linear: DMA lane i gets bytes [16i,16i+16).
// ---------------------------------------------------------------------------
__global__ __launch_bounds__(256) void prep_w1(const float* __restrict__ W1,
                                               unsigned* __restrict__ gW1c) {
    int X = blockIdx.x * 256 + threadIdx.x;       // 0..81919
    int ch = X >> 12;
    int Xc = X & 4095;
    int o  = Xc >> 5;
    int phys_blk = (Xc >> 2) & 7;
    int win = Xc & 3;
    int blk = phys_blk ^ (o & 7);
    int cp  = blk * 4 + win;                      // k-pair index 0..31
    int c   = ch * 64 + 2 * cp;
    float2 f = *(const float2*)(W1 + o * CIN_ + c);
    gW1c[X] = pack2bf(f.x, f.y);
}

// ---------------------------------------------------------------------------
// fused kernel. LDS (u32): smA dbuf 2x4096 | smB 64x44 | smH 64x49 (o-pairs)
// total 14144 u32 = 56,576 B. smP/smG alias smA after the K-loop.
// Wave w (0..7) owns o-rows 16w..16w+15, all 4 n-tiles (hw 0..63, <49 kept).
// A frag read: addr = o*32 + ((4ks+quad)^(o&7))*4  -> per-8-lane phase banks
// distinct. B frag: row stride 44 -> 12*m16+4*quad distinct per phase.
// ---------------------------------------------------------------------------
__global__ __launch_bounds__(512) void fused_kernel(
    const float* __restrict__ F,     // (256,1280,7,7)
    const float* __restrict__ grid,  // (256,7,7,2)
    const float* __restrict__ bbox,  // (256,40,5)
    const float* __restrict__ anc,   // (9,2)
    const unsigned* __restrict__ gW1c,
    const float* __restrict__ B1,    // (128,)
    const float* __restrict__ W2,    // (65,128)
    const float* __restrict__ B2,    // (65,)
    float* __restrict__ out)
{
    __shared__ unsigned lds[14144];
    unsigned* smA = lds;                   // 2 x 4096
    unsigned* smB = lds + 8192;            // [64][44]
    unsigned* smH = lds + 11008;           // [64][49] u32 = (h[2k],h[2k+1]) bf16
    float* smP = (float*)lds;              // 441*6 f32 (aliases smA buf0)
    float* smG = (float*)(lds + 4096);     // 40*5  f32 (aliases smA buf1)

    const int tid  = threadIdx.x;
    const int b    = blockIdx.x;
    const int lane = tid & 63;
    const int w    = tid >> 6;
    const int quad = lane >> 4;
    const int m16  = lane & 15;

    const float* Fb = F + b * (CIN_ * HW_);

    // B staging map: thread -> cp = tid>>4 (0..31), hw = (tid&15) + 16s
    const int cps = tid >> 4;
    const int hwb = tid & 15;

    f32x4 acc[4];
    #pragma unroll
    for (int nt = 0; nt < 4; ++nt) acc[nt] = (f32x4)(0.f);

    float fb0[4], fb1[4];

    // ---- prologue: chunk 0 ----
    {
        const unsigned* g = gW1c + (w * 2) * 256 + lane * 4;
        unsigned* l = smA + (w * 2) * 256;
        gld_lds16(g, l);
        gld_lds16(g + 256, l + 256);
        #pragma unroll
        for (int s = 0; s < 4; ++s) {
            int hw = hwb + 16 * s;
            if (hw < HW_) {
                const float* src = Fb + (2 * cps) * HW_ + hw;
                fb0[s] = src[0]; fb1[s] = src[HW_];
            }
        }
    }
    __syncthreads();          // A0 DMA + F0 regs complete
    #pragma unroll
    for (int s = 0; s < 4; ++s) {
        int hw = hwb + 16 * s;
        if (hw < HW_) smB[hw * 44 + cps] = pack2bf(fb0[s], fb1[s]);
    }
    __syncthreads();          // B0 visible

    const int swz = (m16 & 7);
    for (int ch = 0; ch < NCH; ++ch) {
        const int p = ch & 1;
        if (ch < NCH - 1) {
            // fire-and-forget next chunk: A via DMA into !p, F into regs
            const unsigned* g = gW1c + (ch + 1) * 4096 + (w * 2) * 256 + lane * 4;
            unsigned* l = smA + (p ^ 1) * 4096 + (w * 2) * 256;
            gld_lds16(g, l);
            gld_lds16(g + 256, l + 256);
            const int c0n = (ch + 1) * 64;
            #pragma unroll
            for (int s = 0; s < 4; ++s) {
                int hw = hwb + 16 * s;
                if (hw < HW_) {
                    const float* src = Fb + (c0n + 2 * cps) * HW_ + hw;
                    fb0[s] = src[0]; fb1[s] = src[HW_];
                }
            }
        }
        // compute chunk ch (overlaps the in-flight loads above)
        {
            const unsigned* Ab = smA + p * 4096 + ((w * 16 + m16) << 5);
            bf16x8 a0 = ld_frag(Ab + ((quad ^ swz) << 2));
            bf16x8 a1 = ld_frag(Ab + (((4 + quad) ^ swz) << 2));
            const unsigned* Bb = smB + m16 * 44 + quad * 4;
            #pragma unroll
            for (int nt = 0; nt < 4; ++nt) {
                bf16x8 b0 = ld_frag(Bb + nt * 16 * 44);
                bf16x8 b1 = ld_frag(Bb + nt * 16 * 44 + 16);
                acc[nt] = __builtin_amdgcn_mfma_f32_16x16x32_bf16(a0, b0, acc[nt], 0, 0, 0);
                acc[nt] = __builtin_amdgcn_mfma_f32_16x16x32_bf16(a1, b1, acc[nt], 0, 0, 0);
            }
        }
        __syncthreads();      // drains vmcnt: A[ch+1] landed, F regs in; B reads done
        if (ch < NCH - 1) {
            #pragma unroll
            for (int s = 0; s < 4; ++s) {
                int hw = hwb + 16 * s;
                if (hw < HW_) smB[hw * 44 + cps] = pack2bf(fb0[s], fb1[s]);
            }
        }
        __syncthreads();      // B[ch+1] visible
    }

    // bias + leaky_relu -> smH packed o-pairs. o = 16w + 4*quad + r, hw = 16nt + m16
    #pragma unroll
    for (int nt = 0; nt < 4; ++nt) {
        int hw = nt * 16 + m16;
        if (hw < HW_) {
            #pragma unroll
            for (int rp = 0; rp < 2; ++rp) {
                int o0 = w * 16 + quad * 4 + 2 * rp;
                float v0 = acc[nt][2 * rp]     + B1[o0];
                float v1 = acc[nt][2 * rp + 1] + B1[o0 + 1];
                v0 = v0 > 0.f ? v0 : 0.01f * v0;
                v1 = v1 > 0.f ? v1 : 0.01f * v1;
                smH[(o0 >> 1) * HW_ + hw] = pack2bf(v0, v1);
            }
        }
    }

    // stage IoU inputs into freed smA region (no barrier needed before: disjoint)
    if (tid < NP_) {
        int pp = tid, a = pp / 49, r = pp - a * 49;
        float cx = grid[b * 98 + 2 * r], cy = grid[b * 98 + 2 * r + 1];
        float hx = anc[2 * a] * 0.5f,    hy = anc[2 * a + 1] * 0.5f;
        float x1 = cx - hx, y1 = cy - hy, x2 = cx + hx, y2 = cy + hy;
        smP[pp * 6 + 0] = x1; smP[pp * 6 + 1] = y1;
        smP[pp * 6 + 2] = x2; smP[pp * 6 + 3] = y2;
        smP[pp * 6 + 4] = (x2 - x1) * (y2 - y1);
        smP[pp * 6 + 5] = (fminf(fminf(x1, y1), fminf(x2, y2)) > 0.f) ? 1.f : 0.f;
    }
    if (tid >= 472) {
        int g = tid - 472;
        float x1 = bbox[b * 200 + g * 5 + 0];
        float y1 = bbox[b * 200 + g * 5 + 1];
        float x2 = bbox[b * 200 + g * 5 + 2];
        float y2 = bbox[b * 200 + g * 5 + 3];
        smG[g * 5 + 0] = x1; smG[g * 5 + 1] = y1;
        smG[g * 5 + 2] = x2; smG[g * 5 + 3] = y2;
        smG[g * 5 + 4] = (x2 - x1) * (y2 - y1);
    }
    __syncthreads();          // smH + smP + smG ready

    // GEMM2 (65x49) + epilogue; smH read as packed bf16 pairs (64 u32 / dot)
    for (int idx = tid; idx < OUTD_ * HW_; idx += 512) {
        int o2 = idx / 49;
        int hw = idx - o2 * 49;
        const float2* wr = (const float2*)(W2 + o2 * HID_);
        float s0 = 0.f, s1 = 0.f;
        #pragma unroll 8
        for (int k2 = 0; k2 < 64; ++k2) {
            unsigned hp = smH[k2 * HW_ + hw];
            float2 wv = wr[k2];
            s0 = fmaf(wv.x, bflo(hp), s0);
            s1 = fmaf(wv.y, bfhi(hp), s1);
        }
        float a = B2[o2] + (s0 + s1);

        unsigned int dst;
        float val;
        if (o2 < 36) {
            int an = o2 >> 2, kk = o2 & 3;
            val = (kk < 2) ? (sigmoidf_(a) - 0.5f) : a;
            dst = OFFS_OFF + b * 1764 + an * 196 + kk * 49 + hw;
        } else if (o2 < 45) {
            val = sigmoidf_(a);
            dst = CONF_OFF + b * 441 + (o2 - 36) * 49 + hw;
        } else {
            val = a;
            dst = CLS_OFF + b * 980 + (o2 - 45) * 49 + hw;
        }
        out[dst] = val;
    }

    // IoU: coalesced stores
    for (int idx = tid; idx < NP_ * NGT_; idx += 512) {
        int pp = idx / 40;
        int g  = idx - pp * 40;
        const float* P = smP + pp * 6;
        const float* G = smG + g * 5;
        float tlx = fmaxf(P[0], G[0]);
        float tly = fmaxf(P[1], G[1]);
        float brx = fminf(P[2], G[2]);
        float bry = fminf(P[3], G[3]);
        float dx = fmaxf(brx - tlx, 0.f);
        float dy = fmaxf(bry - tly, 0.f);
        float inter = dx * dy * P[5];
        out[IOU_OFF + b * (NP_ * NGT_) + idx] = inter / (G[4] + P[4] - inter);
    }
}

// ---------------------------------------------------------------------------
// Fallback (R3 structure) if ws_size is too small for gW1c.
// ---------------------------------------------------------------------------
__global__ __launch_bounds__(512) void fused_fallback(
    const float* __restrict__ F, const float* __restrict__ grid,
    const float* __restrict__ bbox, const float* __restrict__ anc,
    const float* __restrict__ W1, const float* __restrict__ B1,
    const float* __restrict__ W2, const float* __restrict__ B2,
    float* __restrict__ out)
{
    __shared__ unsigned lds[4608 + 2304 + 6272];
    unsigned* smA = lds;
    unsigned* smB = lds + 4608;
    float*    smH = (float*)(lds + 4608 + 2304);
    float* smP = (float*)lds;
    float* smG = (float*)(lds + 4608);

    const int tid  = threadIdx.x;
    const int b    = blockIdx.x;
    const int lane = tid & 63;
    const int w    = tid >> 6;
    const int quad = lane >> 4;
    const int m16  = lane & 15;
    const float* Fb = F + b * (CIN_ * HW_);

    f32x4 acc[4];
    #pragma unroll
    for (int nt = 0; nt < 4; ++nt) acc[nt] = (f32x4)(0.f);

    for (int ch = 0; ch < NCH; ++ch) {
        const int c0 = ch * 64;
        __syncthreads();
        #pragma unroll
        for (int rr = 0; rr < 8; ++rr) {
            int pi = tid + rr * 512;
            int o = pi >> 5, cp = pi & 31;
            float2 f = *(const float2*)(F /*unused*/, (const float2*)nullptr == nullptr ?
                        (const float2*)( ( (const float*)0 ) ) : (const float2*)0), ff;
            (void)f; (void)ff;
            float2 fx = *(const float2*)(((const float*)W1) + o * CIN_ + c0 + 2 * cp);
            smA[o * 36 + cp] = pack2bf(fx.x, fx.y);
        }
        for (int pi = tid; pi < 32 * 49; pi += 512) {
            int cp = pi / 49;
            int hw = pi - cp * 49;
            const float* src = Fb + (c0 + 2 * cp) * HW_ + hw;
            smB[hw * 36 + cp] = pack2bf(src[0], src[HW_]);
        }
        __syncthreads();
        const unsigned* Ab = smA + (w * 16 + m16) * 36 + quad * 4;
        const unsigned* Bb = smB + m16 * 36 + quad * 4;
        #pragma unroll
        for (int ks = 0; ks < 2; ++ks) {
            bf16x8 af = ld_frag(Ab + ks * 16);
            #pragma unroll
            for (int nt = 0; nt < 4; ++nt) {
                bf16x8 bf = ld_frag(Bb + nt * 16 * 36 + ks * 16);
                acc[nt] = __builtin_amdgcn_mfma_f32_16x16x32_bf16(af, bf, acc[nt], 0, 0, 0);
            }
        }
    }
    #pragma unroll
    for (int nt = 0; nt < 4; ++nt) {
        int hw = nt * 16 + m16;
        if (hw < HW_) {
            #pragma unroll
            for (int r = 0; r < 4; ++r) {
                int o = w * 16 + quad * 4 + r;
                float v = acc[nt][r] + B1[o];
                v = v > 0.f ? v : 0.01f * v;
                smH[o * HW_ + hw] = v;
            }
        }
    }
    __syncthreads();
    if (tid < NP_) {
        int pp = tid, a = pp / 49, r = pp - a * 49;
        float cx = grid[b * 98 + 2 * r], cy = grid[b * 98 + 2 * r + 1];
        float hx = anc[2 * a] * 0.5f,    hy = anc[2 * a + 1] * 0.5f;
        float x1 = cx - hx, y1 = cy - hy, x2 = cx + hx, y2 = cy + hy;
        smP[pp * 6 + 0] = x1; smP[pp * 6 + 1] = y1;
        smP[pp * 6 + 2] = x2; smP[pp * 6 + 3] = y2;
        smP[pp * 6 + 4] = (x2 - x1) * (y2 - y1);
        smP[pp * 6 + 5] = (fminf(fminf(x1, y1), fminf(x2, y2)) > 0.f) ? 1.f : 0.f;
    }
    if (tid >= 472) {
        int g = tid - 472;
        float x1 = bbox[b * 200 + g * 5 + 0];
        float y1 = bbox[b * 200 + g * 5 + 1];
        float x2 = bbox[b * 200 + g * 5 + 2];
        float y2 = bbox[b * 200 + g * 5 + 3];
        smG[g * 5 + 0] = x1; smG[g * 5 + 1] = y1;
        smG[g * 5 + 2] = x2; smG[g * 5 + 3] = y2;
        smG[g * 5 + 4] = (x2 - x1) * (y2 - y1);
    }
    for (int idx = tid; idx < OUTD_ * HW_; idx += 512) {
        int o2 = idx / 49;
        int hw = idx - o2 * 49;
        const float4* wr = (const float4*)(W2 + o2 * HID_);
        const float*  hc = smH + hw;
        float s0 = 0.f, s1 = 0.f, s2 = 0.f, s3 = 0.f;
        #pragma unroll 8
        for (int k4 = 0; k4 < 32; ++k4) {
            float4 wv = wr[k4];
            s0 = fmaf(wv.x, hc[(4 * k4 + 0) * HW_], s0);
            s1 = fmaf(wv.y, hc[(4 * k4 + 1) * HW_], s1);
            s2 = fmaf(wv.z, hc[(4 * k4 + 2) * HW_], s2);
            s3 = fmaf(wv.w, hc[(4 * k4 + 3) * HW_], s3);
        }
        float a = B2[o2] + ((s0 + s1) + (s2 + s3));
        unsigned int dst; float val;
        if (o2 < 36) { int an = o2 >> 2, kk = o2 & 3;
            val = (kk < 2) ? (sigmoidf_(a) - 0.5f) : a;
            dst = OFFS_OFF + b * 1764 + an * 196 + kk * 49 + hw;
        } else if (o2 < 45) { val = sigmoidf_(a);
            dst = CONF_OFF + b * 441 + (o2 - 36) * 49 + hw;
        } else { val = a;
            dst = CLS_OFF + b * 980 + (o2 - 45) * 49 + hw; }
        out[dst] = val;
    }
    __syncthreads();
    for (int idx = tid; idx < NP_ * NGT_; idx += 512) {
        int pp = idx / 40;
        int g  = idx - pp * 40;
        const float* P = smP + pp * 6;
        const float* G = smG + g * 5;
        float tlx = fmaxf(P[0], G[0]);
        float tly = fmaxf(P[1], G[1]);
        float brx = fminf(P[2], G[2]);
        float bry = fminf(P[3], G[3]);
        float dx = fmaxf(brx - tlx, 0.f);
        float dy = fmaxf(bry - tly, 0.f);
        float inter = dx * dy * P[5];
        out[IOU_OFF + b * (NP_ * NGT_) + idx] = inter / (G[4] + P[4] - inter);
    }
}

extern "C" void kernel_launch(void* const* d_in, const int* in_sizes, int n_in,
                              void* d_out, int out_size, void* d_ws, size_t ws_size,
                              hipStream_t stream) {
    const float* F  = (const float*)d_in[0];
    const float* G  = (const float*)d_in[1];
    const float* BB = (const float*)d_in[2];
    const float* AN = (const float*)d_in[3];
    const float* W1 = (const float*)d_in[4];
    const float* B1 = (const float*)d_in[5];
    const float* W2 = (const float*)d_in[6];
    const float* B2 = (const float*)d_in[7];
    float* out = (float*)d_out;

    if (ws_size >= (size_t)W1C_U32 * 4) {
        unsigned* gW1c = (unsigned*)d_ws;
        prep_w1<<<320, 256, 0, stream>>>(W1, gW1c);
        fused_kernel<<<256, 512, 0, stream>>>(F, G, BB, AN, gW1c, B1, W2, B2, out);
    } else {
        fused_fallback<<<256, 512, 0, stream>>>(F, G, BB, AN, W1, B1, W2, B2, out);
    }
}

// Round 5
// 141.308 us; speedup vs baseline: 1.9373x; 1.0545x over previous
//
#include <hip/hip_runtime.h>

// SingleStageDetector fused head+IoU, R5. f32 I/O; GEMM1 via bf16 MFMA.
// R5 structure: whole F[b] image staged to LDS as packed bf16 ONCE; K-loop is
// BARRIER-FREE (B-frags from LDS ds_read_b128, A-frags from a prep-built
// fragment-ready W1 image via coalesced global_load_dwordx4 into VGPRs).

#define CIN_  1280
#define HW_   49
#define HID_  128
#define OUTD_ 65
#define NGT_  40
#define NP_   441
#define NCH   20          // 1280 / 64 channels per chunk

// flat output offsets (elements), reference return order
#define CONF_OFF 0
#define OFFS_OFF 112896   // 256*9*49
#define CLS_OFF  564480   // + 256*9*4*49
#define IOU_OFF  815360   // + 256*20*49 ; total 5,331,200

#define W1F_U32  81920    // 20ch * 16 frags * 64 lanes * 4 u32 = 320 KB in d_ws

#define SF_STRIDE 644     // u32 row stride: 644 % 32 == 4 -> frag start banks 4*m16
#define SF_SIZE   (49 * SF_STRIDE)   // 31556 u32 = 126,224 B

typedef __bf16 bf16x8 __attribute__((ext_vector_type(8)));
typedef float  f32x4  __attribute__((ext_vector_type(4)));

__device__ __forceinline__ unsigned pack2bf(float lo, float hi) {
    unsigned a = __float_as_uint(lo);
    unsigned b = __float_as_uint(hi);
    a = (a + 0x7FFFu + ((a >> 16) & 1u)) >> 16;   // RNE f32->bf16
    b = (b + 0x7FFFu + ((b >> 16) & 1u)) >> 16;
    return a | (b << 16);
}
__device__ __forceinline__ float bflo(unsigned u) { return __uint_as_float(u << 16); }
__device__ __forceinline__ float bfhi(unsigned u) { return __uint_as_float(u & 0xFFFF0000u); }
__device__ __forceinline__ float sigmoidf_(float v) { return 1.f / (1.f + __expf(-v)); }

__device__ __forceinline__ bf16x8 ld_frag(const unsigned* p) {
    union { uint4 u; bf16x8 v; } x;
    x.u = *(const uint4*)p;                       // 16B-aligned ds_read_b128
    return x.v;
}
__device__ __forceinline__ bf16x8 as_bf(uint4 u) {
    union { uint4 u; bf16x8 v; } x; x.u = u; return x.v;
}

// ---------------------------------------------------------------------------
// prep_w1: W1 (128,1280) f32 -> A-fragment-ready bf16 image gW1f.
// u32 index X = (((ch*8 + w)*2 + ks)*64 + lane)*4 + sub, holding W1[o][c..c+1]
// with o = w*16 + (lane&15), c = ch*64 + ks*32 + (lane>>4)*8 + sub*2.
// Main kernel A-frag = global_load_dwordx4 at frag_base + lane*16 (coalesced).
// ---------------------------------------------------------------------------
__global__ __launch_bounds__(256) void prep_w1(const float* __restrict__ W1,
                                               unsigned* __restrict__ gW1f) {
    int X = blockIdx.x * 256 + threadIdx.x;       // 0..81919
    int sub  = X & 3;
    int lane = (X >> 2) & 63;
    int r    = X >> 8;            // 0..319
    int ks   = r & 1;
    int w    = (r >> 1) & 7;
    int ch   = r >> 4;
    int o = w * 16 + (lane & 15);
    int c = ch * 64 + ks * 32 + (lane >> 4) * 8 + sub * 2;
    float2 f = *(const float2*)(W1 + o * CIN_ + c);
    gW1f[X] = pack2bf(f.x, f.y);
}

// ---------------------------------------------------------------------------
// fused kernel, grid 256 x 512. Wave w = M-tile (o rows 16w..16w+15).
// smF[hw][cp] packed bf16 c-pairs, stride 644. N-tiles: nt<3 -> hw=nt*16+m16;
// nt=3 -> lane m16==0 maps to hw 48, others duplicate rows 0..14 (discarded).
// ---------------------------------------------------------------------------
__global__ __launch_bounds__(512) void fused_kernel(
    const float* __restrict__ F,     // (256,1280,7,7)
    const float* __restrict__ grid,  // (256,7,7,2)
    const float* __restrict__ bbox,  // (256,40,5)
    const float* __restrict__ anc,   // (9,2)
    const unsigned* __restrict__ gW1f,
    const float* __restrict__ B1,    // (128,)
    const float* __restrict__ W2,    // (65,128)
    const float* __restrict__ B2,    // (65,)
    float* __restrict__ out)
{
    __shared__ unsigned lds[SF_SIZE];
    unsigned* smF = lds;
    unsigned* smH = lds;                          // aliased after K-loop barrier
    float* smP = (float*)(lds + 3136);            // 441*6 f32
    float* smG = (float*)(lds + 3136 + 2646);     // 40*5 f32

    const int tid  = threadIdx.x;
    const int b    = blockIdx.x;
    const int lane = tid & 63;
    const int w    = tid >> 6;     // wave = M-tile
    const int quad = lane >> 4;
    const int m16  = lane & 15;

    const float* Fb = F + b * (CIN_ * HW_);

    // ---- stage whole F image -> smF (packed bf16 c-pairs), one barrier ----
    for (int i = tid; i < 640 * 49; i += 512) {
        int cp = i / 49;
        int hw = i - cp * 49;
        const float* s = Fb + (2 * cp) * HW_ + hw;
        smF[hw * SF_STRIDE + cp] = pack2bf(s[0], s[HW_]);
    }
    __syncthreads();

    // per-lane B-frag row bases (col offset = ch*32 + ks*16 + quad*4)
    const int row3 = (m16 == 0) ? 48 : (m16 - 1);
    const unsigned* Bb[4] = {
        smF + (0 * 16 + m16) * SF_STRIDE + quad * 4,
        smF + (1 * 16 + m16) * SF_STRIDE + quad * 4,
        smF + (2 * 16 + m16) * SF_STRIDE + quad * 4,
        smF + row3 * SF_STRIDE + quad * 4
    };

    // A-frag pointer: + ch*1024 + ks*64 (uint4 units)
    const uint4* Aw = (const uint4*)gW1f + (w * 2) * 64 + lane;

    f32x4 acc[4];
    #pragma unroll
    for (int nt = 0; nt < 4; ++nt) acc[nt] = (f32x4)(0.f);

    uint4 a0 = Aw[0];
    uint4 a1 = Aw[64];
    for (int ch = 0; ch < NCH; ++ch) {
        uint4 na0, na1;
        if (ch < NCH - 1) {                       // prefetch next A (no barrier)
            na0 = Aw[(ch + 1) * 1024];
            na1 = Aw[(ch + 1) * 1024 + 64];
        }
        const int coff = ch * 32;
        bf16x8 aa0 = as_bf(a0);
        bf16x8 aa1 = as_bf(a1);
        #pragma unroll
        for (int nt = 0; nt < 4; ++nt) {
            bf16x8 b0 = ld_frag(Bb[nt] + coff);
            bf16x8 b1 = ld_frag(Bb[nt] + coff + 16);
            acc[nt] = __builtin_amdgcn_mfma_f32_16x16x32_bf16(aa0, b0, acc[nt], 0, 0, 0);
            acc[nt] = __builtin_amdgcn_mfma_f32_16x16x32_bf16(aa1, b1, acc[nt], 0, 0, 0);
        }
        a0 = na0; a1 = na1;
    }

    __syncthreads();   // all waves done reading smF; safe to alias

    // bias + leaky_relu -> smH packed o-pairs [o/2][hw]
    #pragma unroll
    for (int nt = 0; nt < 4; ++nt) {
        int hw = (nt < 3) ? (nt * 16 + m16) : ((m16 == 0) ? 48 : -1);
        if (hw >= 0) {
            #pragma unroll
            for (int rp = 0; rp < 2; ++rp) {
                int o0 = w * 16 + quad * 4 + 2 * rp;
                float v0 = acc[nt][2 * rp]     + B1[o0];
                float v1 = acc[nt][2 * rp + 1] + B1[o0 + 1];
                v0 = v0 > 0.f ? v0 : 0.01f * v0;
                v1 = v1 > 0.f ? v1 : 0.01f * v1;
                smH[(o0 >> 1) * HW_ + hw] = pack2bf(v0, v1);
            }
        }
    }

    // stage IoU inputs (disjoint LDS region; wait for smP/smG at next barrier)
    if (tid < NP_) {
        int pp = tid, a = pp / 49, r = pp - a * 49;
        float cx = grid[b * 98 + 2 * r], cy = grid[b * 98 + 2 * r + 1];
        float hx = anc[2 * a] * 0.5f,    hy = anc[2 * a + 1] * 0.5f;
        float x1 = cx - hx, y1 = cy - hy, x2 = cx + hx, y2 = cy + hy;
        smP[pp * 6 + 0] = x1; smP[pp * 6 + 1] = y1;
        smP[pp * 6 + 2] = x2; smP[pp * 6 + 3] = y2;
        smP[pp * 6 + 4] = (x2 - x1) * (y2 - y1);
        smP[pp * 6 + 5] = (fminf(fminf(x1, y1), fminf(x2, y2)) > 0.f) ? 1.f : 0.f;
    }
    if (tid >= 472) {
        int g = tid - 472;
        float x1 = bbox[b * 200 + g * 5 + 0];
        float y1 = bbox[b * 200 + g * 5 + 1];
        float x2 = bbox[b * 200 + g * 5 + 2];
        float y2 = bbox[b * 200 + g * 5 + 3];
        smG[g * 5 + 0] = x1; smG[g * 5 + 1] = y1;
        smG[g * 5 + 2] = x2; smG[g * 5 + 3] = y2;
        smG[g * 5 + 4] = (x2 - x1) * (y2 - y1);
    }
    __syncthreads();   // smH + smP + smG ready

    // GEMM2 (65x49) + epilogue; smH as packed bf16 pairs
    for (int idx = tid; idx < OUTD_ * HW_; idx += 512) {
        int o2 = idx / 49;
        int hw = idx - o2 * 49;
        const float2* wr = (const float2*)(W2 + o2 * HID_);
        float s0 = 0.f, s1 = 0.f;
        #pragma unroll 8
        for (int k2 = 0; k2 < 64; ++k2) {
            unsigned hp = smH[k2 * HW_ + hw];
            float2 wv = wr[k2];
            s0 = fmaf(wv.x, bflo(hp), s0);
            s1 = fmaf(wv.y, bfhi(hp), s1);
        }
        float a = B2[o2] + (s0 + s1);

        unsigned int dst;
        float val;
        if (o2 < 36) {
            int an = o2 >> 2, kk = o2 & 3;
            val = (kk < 2) ? (sigmoidf_(a) - 0.5f) : a;
            dst = OFFS_OFF + b * 1764 + an * 196 + kk * 49 + hw;
        } else if (o2 < 45) {
            val = sigmoidf_(a);
            dst = CONF_OFF + b * 441 + (o2 - 36) * 49 + hw;
        } else {
            val = a;
            dst = CLS_OFF + b * 980 + (o2 - 45) * 49 + hw;
        }
        out[dst] = val;
    }

    // IoU: coalesced stores
    for (int idx = tid; idx < NP_ * NGT_; idx += 512) {
        int pp = idx / 40;
        int g  = idx - pp * 40;
        const float* P = smP + pp * 6;
        const float* G = smG + g * 5;
        float tlx = fmaxf(P[0], G[0]);
        float tly = fmaxf(P[1], G[1]);
        float brx = fminf(P[2], G[2]);
        float bry = fminf(P[3], G[3]);
        float dx = fmaxf(brx - tlx, 0.f);
        float dy = fmaxf(bry - tly, 0.f);
        float inter = dx * dy * P[5];
        out[IOU_OFF + b * (NP_ * NGT_) + idx] = inter / (G[4] + P[4] - inter);
    }
}

// ---------------------------------------------------------------------------
// Fallback (R3 structure, cleaned) if ws_size can't hold gW1f.
// ---------------------------------------------------------------------------
__global__ __launch_bounds__(512) void fused_fallback(
    const float* __restrict__ F, const float* __restrict__ grid,
    const float* __restrict__ bbox, const float* __restrict__ anc,
    const float* __restrict__ W1, const float* __restrict__ B1,
    const float* __restrict__ W2, const float* __restrict__ B2,
    float* __restrict__ out)
{
    __shared__ unsigned lds[4608 + 2304 + 6272];
    unsigned* smA = lds;
    unsigned* smB = lds + 4608;
    float*    smH = (float*)(lds + 4608 + 2304);
    float* smP = (float*)lds;
    float* smG = (float*)(lds + 4608);

    const int tid  = threadIdx.x;
    const int b    = blockIdx.x;
    const int lane = tid & 63;
    const int w    = tid >> 6;
    const int quad = lane >> 4;
    const int m16  = lane & 15;
    const float* Fb = F + b * (CIN_ * HW_);

    f32x4 acc[4];
    #pragma unroll
    for (int nt = 0; nt < 4; ++nt) acc[nt] = (f32x4)(0.f);

    for (int ch = 0; ch < NCH; ++ch) {
        const int c0 = ch * 64;
        __syncthreads();
        #pragma unroll
        for (int rr = 0; rr < 8; ++rr) {
            int pi = tid + rr * 512;
            int o = pi >> 5, cp = pi & 31;
            float2 fx = *(const float2*)(W1 + o * CIN_ + c0 + 2 * cp);
            smA[o * 36 + cp] = pack2bf(fx.x, fx.y);
        }
        for (int pi = tid; pi < 32 * 49; pi += 512) {
            int cp = pi / 49;
            int hw = pi - cp * 49;
            const float* src = Fb + (c0 + 2 * cp) * HW_ + hw;
            smB[hw * 36 + cp] = pack2bf(src[0], src[HW_]);
        }
        __syncthreads();
        const unsigned* Ab = smA + (w * 16 + m16) * 36 + quad * 4;
        const unsigned* Bb = smB + m16 * 36 + quad * 4;
        #pragma unroll
        for (int ks = 0; ks < 2; ++ks) {
            bf16x8 af = ld_frag(Ab + ks * 16);
            #pragma unroll
            for (int nt = 0; nt < 4; ++nt) {
                bf16x8 bf = ld_frag(Bb + nt * 16 * 36 + ks * 16);
                acc[nt] = __builtin_amdgcn_mfma_f32_16x16x32_bf16(af, bf, acc[nt], 0, 0, 0);
            }
        }
    }
    #pragma unroll
    for (int nt = 0; nt < 4; ++nt) {
        int hw = nt * 16 + m16;
        if (hw < HW_) {
            #pragma unroll
            for (int r = 0; r < 4; ++r) {
                int o = w * 16 + quad * 4 + r;
                float v = acc[nt][r] + B1[o];
                v = v > 0.f ? v : 0.01f * v;
                smH[o * HW_ + hw] = v;
            }
        }
    }
    __syncthreads();
    if (tid < NP_) {
        int pp = tid, a = pp / 49, r = pp - a * 49;
        float cx = grid[b * 98 + 2 * r], cy = grid[b * 98 + 2 * r + 1];
        float hx = anc[2 * a] * 0.5f,    hy = anc[2 * a + 1] * 0.5f;
        float x1 = cx - hx, y1 = cy - hy, x2 = cx + hx, y2 = cy + hy;
        smP[pp * 6 + 0] = x1; smP[pp * 6 + 1] = y1;
        smP[pp * 6 + 2] = x2; smP[pp * 6 + 3] = y2;
        smP[pp * 6 + 4] = (x2 - x1) * (y2 - y1);
        smP[pp * 6 + 5] = (fminf(fminf(x1, y1), fminf(x2, y2)) > 0.f) ? 1.f : 0.f;
    }
    if (tid >= 472) {
        int g = tid - 472;
        float x1 = bbox[b * 200 + g * 5 + 0];
        float y1 = bbox[b * 200 + g * 5 + 1];
        float x2 = bbox[b * 200 + g * 5 + 2];
        float y2 = bbox[b * 200 + g * 5 + 3];
        smG[g * 5 + 0] = x1; smG[g * 5 + 1] = y1;
        smG[g * 5 + 2] = x2; smG[g * 5 + 3] = y2;
        smG[g * 5 + 4] = (x2 - x1) * (y2 - y1);
    }
    for (int idx = tid; idx < OUTD_ * HW_; idx += 512) {
        int o2 = idx / 49;
        int hw = idx - o2 * 49;
        const float4* wr = (const float4*)(W2 + o2 * HID_);
        const float*  hc = smH + hw;
        float s0 = 0.f, s1 = 0.f, s2 = 0.f, s3 = 0.f;
        #pragma unroll 8
        for (int k4 = 0; k4 < 32; ++k4) {
            float4 wv = wr[k4];
            s0 = fmaf(wv.x, hc[(4 * k4 + 0) * HW_], s0);
            s1 = fmaf(wv.y, hc[(4 * k4 + 1) * HW_], s1);
            s2 = fmaf(wv.z, hc[(4 * k4 + 2) * HW_], s2);
            s3 = fmaf(wv.w, hc[(4 * k4 + 3) * HW_], s3);
        }
        float a = B2[o2] + ((s0 + s1) + (s2 + s3));
        unsigned int dst; float val;
        if (o2 < 36) { int an = o2 >> 2, kk = o2 & 3;
            val = (kk < 2) ? (sigmoidf_(a) - 0.5f) : a;
            dst = OFFS_OFF + b * 1764 + an * 196 + kk * 49 + hw;
        } else if (o2 < 45) { val = sigmoidf_(a);
            dst = CONF_OFF + b * 441 + (o2 - 36) * 49 + hw;
        } else { val = a;
            dst = CLS_OFF + b * 980 + (o2 - 45) * 49 + hw; }
        out[dst] = val;
    }
    __syncthreads();
    for (int idx = tid; idx < NP_ * NGT_; idx += 512) {
        int pp = idx / 40;
        int g  = idx - pp * 40;
        const float* P = smP + pp * 6;
        const float* G = smG + g * 5;
        float tlx = fmaxf(P[0], G[0]);
        float tly = fmaxf(P[1], G[1]);
        float brx = fminf(P[2], G[2]);
        float bry = fminf(P[3], G[3]);
        float dx = fmaxf(brx - tlx, 0.f);
        float dy = fmaxf(bry - tly, 0.f);
        float inter = dx * dy * P[5];
        out[IOU_OFF + b * (NP_ * NGT_) + idx] = inter / (G[4] + P[4] - inter);
    }
}

extern "C" void kernel_launch(void* const* d_in, const int* in_sizes, int n_in,
                              void* d_out, int out_size, void* d_ws, size_t ws_size,
                              hipStream_t stream) {
    const float* F  = (const float*)d_in[0];
    const float* G  = (const float*)d_in[1];
    const float* BB = (const float*)d_in[2];
    const float* AN = (const float*)d_in[3];
    const float* W1 = (const float*)d_in[4];
    const float* B1 = (const float*)d_in[5];
    const float* W2 = (const float*)d_in[6];
    const float* B2 = (const float*)d_in[7];
    float* out = (float*)d_out;

    if (ws_size >= (size_t)W1F_U32 * 4) {
        unsigned* gW1f = (unsigned*)d_ws;
        prep_w1<<<320, 256, 0, stream>>>(W1, gW1f);
        fused_kernel<<<256, 512, 0, stream>>>(F, G, BB, AN, gW1f, B1, W2, B2, out);
    } else {
        fused_fallback<<<256, 512, 0, stream>>>(F, G, BB, AN, W1, B1, W2, B2, out);
    }
}

// Round 6
// 140.478 us; speedup vs baseline: 1.9487x; 1.0059x over previous
//
#include <hip/hip_runtime.h>

// SingleStageDetector fused head+IoU, R6. f32 I/O; both GEMMs via bf16 MFMA.
// Path A (needs 13.2 MB ws): prep W1/W2 fragment images -> kernel A: 4-way
// K-split GEMM1 partials (bf16-packed) + IoU quarters -> kernel B: partial sum
// + bias/leaky + MFMA GEMM2 + epilogue. 32KB LDS/block in A => ~4 blocks/CU.

#define CIN_  1280
#define HW_   49
#define HID_  128
#define OUTD_ 65
#define NGT_  40
#define NP_   441

// flat output offsets (elements), reference return order
#define CONF_OFF 0
#define OFFS_OFF 112896   // 256*9*49
#define CLS_OFF  564480   // + 256*9*4*49
#define IOU_OFF  815360   // + 256*20*49 ; total 5,331,200

// workspace layout (u32 units)
#define WS_W1F   0        // 81920 u32: W1 frags, idx ((K32*8+mt)*64+lane)*4+sub
#define WS_W2F   81920    // 5120 u32:  W2 frags, idx ((ks2*5+mt2)*64+lane)*4+sub
#define WS_PART  87040    // 256*4*64*49 = 3,211,264 u32 bf16-pair partials
#define WS_NEED_FULL ((87040u + 3211264u) * 4u)    // 13,193,216 B
#define WS_NEED_MID  (81920u * 4u)                 // 327,680 B

typedef __bf16 bf16x8 __attribute__((ext_vector_type(8)));
typedef float  f32x4  __attribute__((ext_vector_type(4)));

__device__ __forceinline__ unsigned pack2bf(float lo, float hi) {
    unsigned a = __float_as_uint(lo);
    unsigned b = __float_as_uint(hi);
    a = (a + 0x7FFFu + ((a >> 16) & 1u)) >> 16;   // RNE f32->bf16
    b = (b + 0x7FFFu + ((b >> 16) & 1u)) >> 16;
    return a | (b << 16);
}
__device__ __forceinline__ float bflo(unsigned u) { return __uint_as_float(u << 16); }
__device__ __forceinline__ float bfhi(unsigned u) { return __uint_as_float(u & 0xFFFF0000u); }
__device__ __forceinline__ float sigmoidf_(float v) { return 1.f / (1.f + __expf(-v)); }

__device__ __forceinline__ bf16x8 ld_frag(const unsigned* p) {
    union { uint4 u; bf16x8 v; } x;
    x.u = *(const uint4*)p;                       // 16B-aligned ds_read_b128
    return x.v;
}
__device__ __forceinline__ bf16x8 as_bf(uint4 u) {
    union { uint4 u; bf16x8 v; } x; x.u = u; return x.v;
}

// ---------------------------------------------------------------------------
// prep_w1f: W1 (128,1280) -> frag image. frag id f = K32*8 + mt (K32=0..39).
// value at (f, lane, sub) = pack(W1[mt*16+(lane&15)][K32*32+(lane>>4)*8+sub*2 .. +1])
// ---------------------------------------------------------------------------
__global__ __launch_bounds__(256) void prep_w1f(const float* __restrict__ W1,
                                                unsigned* __restrict__ g) {
    int X = blockIdx.x * 256 + threadIdx.x;       // 0..81919
    int sub = X & 3, lane = (X >> 2) & 63, f = X >> 8;
    int mt = f & 7, K32 = f >> 3;
    int o = mt * 16 + (lane & 15);
    int c = K32 * 32 + (lane >> 4) * 8 + sub * 2;
    float2 v = *(const float2*)(W1 + o * CIN_ + c);
    g[X] = pack2bf(v.x, v.y);
}

// prep_w2f: W2 (65,128) -> frag image, rows 65..79 zero. f2 = ks2*5 + mt2.
__global__ __launch_bounds__(256) void prep_w2f(const float* __restrict__ W2,
                                                unsigned* __restrict__ g) {
    int X = blockIdx.x * 256 + threadIdx.x;       // 0..5119
    int sub = X & 3, lane = (X >> 2) & 63, f = X >> 8;
    int mt2 = f % 5, ks2 = f / 5;
    int o2 = mt2 * 16 + (lane & 15);
    int c = ks2 * 32 + (lane >> 4) * 8 + sub * 2;
    unsigned val = 0;
    if (o2 < OUTD_) {
        float2 v = *(const float2*)(W2 + o2 * HID_ + c);
        val = pack2bf(v.x, v.y);
    }
    g[X] = val;
}

// ---------------------------------------------------------------------------
// Kernel A: block (b, ksp) computes partial h over channels [ksp*320,+320)
// (bf16-pair packed, no bias/act) + IoU quarter ksp. 256 thr = 4 waves; wave w
// owns m-tiles 2w, 2w+1. smF: [hw<49][cp<160] stride 164 (==4 mod 32 ->
// conflict-free b128 frags; staging via b128 writes, conflict-free).
// ---------------------------------------------------------------------------
__global__ __launch_bounds__(256) void gemm1_partial(
    const float* __restrict__ F, const float* __restrict__ grid,
    const float* __restrict__ bbox, const float* __restrict__ anc,
    const unsigned* __restrict__ gW1f,
    unsigned* __restrict__ wsp, float* __restrict__ out)
{
    __shared__ __align__(16) unsigned smF[49 * 164];   // 32,144 B
    float* smP = (float*)smF;          // 441*6 f32 (aliased after K-loop)
    float* smG = (float*)smF + 2646;   // 40*5 f32

    const int tid  = threadIdx.x;
    const int b    = blockIdx.x >> 2;
    const int ksp  = blockIdx.x & 3;
    const int lane = tid & 63;
    const int w    = tid >> 6;         // 0..3
    const int quad = lane >> 4;
    const int m16  = lane & 15;

    const float* Fb = F + b * (CIN_ * HW_) + ksp * 320 * HW_;

    // ---- stage 320 channels as packed bf16 pairs: [hw][cp], b128 writes ----
    for (int idx = tid; idx < 1960; idx += 256) {      // 40 cb x 49 hw
        int cb = idx / 49;
        int hw = idx - cb * 49;
        const float* s = Fb + cb * 392 + hw;           // cb*8 channels
        float v0 = s[0],   v1 = s[49],  v2 = s[98],  v3 = s[147];
        float v4 = s[196], v5 = s[245], v6 = s[294], v7 = s[343];
        uint4 pk;
        pk.x = pack2bf(v0, v1); pk.y = pack2bf(v2, v3);
        pk.z = pack2bf(v4, v5); pk.w = pack2bf(v6, v7);
        *(uint4*)(smF + hw * 164 + cb * 4) = pk;
    }
    __syncthreads();

    const int row3 = (m16 == 0) ? 48 : (m16 - 1);      // nt=3: only hw 48 valid
    const unsigned* Bb[4] = {
        smF + m16 * 164 + quad * 4,
        smF + (16 + m16) * 164 + quad * 4,
        smF + (32 + m16) * 164 + quad * 4,
        smF + row3 * 164 + quad * 4
    };

    const int mt0 = w * 2, mt1 = mt0 + 1;
    const int K32b = ksp * 10;
    const uint4* Ap0 = (const uint4*)gW1f + (K32b * 8 + mt0) * 64 + lane;
    const uint4* Ap1 = (const uint4*)gW1f + (K32b * 8 + mt1) * 64 + lane;

    f32x4 acc0[4], acc1[4];
    #pragma unroll
    for (int nt = 0; nt < 4; ++nt) { acc0[nt] = (f32x4)(0.f); acc1[nt] = (f32x4)(0.f); }

    uint4 a0 = Ap0[0], a1 = Ap1[0];
    for (int k = 0; k < 10; ++k) {
        uint4 n0, n1;
        if (k < 9) { n0 = Ap0[(k + 1) * 512]; n1 = Ap1[(k + 1) * 512]; }
        bf16x8 A0 = as_bf(a0), A1 = as_bf(a1);
        const int co = k * 16;
        #pragma unroll
        for (int nt = 0; nt < 4; ++nt) {
            bf16x8 Bf = ld_frag(Bb[nt] + co);
            acc0[nt] = __builtin_amdgcn_mfma_f32_16x16x32_bf16(A0, Bf, acc0[nt], 0, 0, 0);
            acc1[nt] = __builtin_amdgcn_mfma_f32_16x16x32_bf16(A1, Bf, acc1[nt], 0, 0, 0);
        }
        a0 = n0; a1 = n1;
    }

    // ---- store bf16-packed partials: wsp[((b*4+ksp)*64+op)*49+hw] ----
    const unsigned pbase = (unsigned)(b * 4 + ksp) * 64u;
    #pragma unroll
    for (int m = 0; m < 2; ++m) {
        const f32x4* ac = m ? acc1 : acc0;
        int mtg = w * 2 + m;
        #pragma unroll
        for (int nt = 0; nt < 4; ++nt) {
            int hw = (nt < 3) ? (nt * 16 + m16) : ((m16 == 0) ? 48 : -1);
            if (hw >= 0) {
                #pragma unroll
                for (int rp = 0; rp < 2; ++rp) {
                    int op = mtg * 8 + quad * 2 + rp;
                    wsp[(pbase + op) * 49u + hw] = pack2bf(ac[nt][2 * rp], ac[nt][2 * rp + 1]);
                }
            }
        }
    }
    __syncthreads();   // all frag reads done; smF reusable

    // ---- stage IoU inputs ----
    for (int pp = tid; pp < NP_; pp += 256) {
        int a = pp / 49, r = pp - a * 49;
        float cx = grid[b * 98 + 2 * r], cy = grid[b * 98 + 2 * r + 1];
        float hx = anc[2 * a] * 0.5f,    hy = anc[2 * a + 1] * 0.5f;
        float x1 = cx - hx, y1 = cy - hy, x2 = cx + hx, y2 = cy + hy;
        smP[pp * 6 + 0] = x1; smP[pp * 6 + 1] = y1;
        smP[pp * 6 + 2] = x2; smP[pp * 6 + 3] = y2;
        smP[pp * 6 + 4] = (x2 - x1) * (y2 - y1);
        smP[pp * 6 + 5] = (fminf(fminf(x1, y1), fminf(x2, y2)) > 0.f) ? 1.f : 0.f;
    }
    if (tid < NGT_) {
        int g = tid;
        float x1 = bbox[b * 200 + g * 5 + 0];
        float y1 = bbox[b * 200 + g * 5 + 1];
        float x2 = bbox[b * 200 + g * 5 + 2];
        float y2 = bbox[b * 200 + g * 5 + 3];
        smG[g * 5 + 0] = x1; smG[g * 5 + 1] = y1;
        smG[g * 5 + 2] = x2; smG[g * 5 + 3] = y2;
        smG[g * 5 + 4] = (x2 - x1) * (y2 - y1);
    }
    __syncthreads();

    // ---- IoU quarter: idx in [ksp*4410, +4410) ----
    for (int ii = tid; ii < 4410; ii += 256) {
        int idx = ksp * 4410 + ii;
        int p = idx / 40;
        int g = idx - p * 40;
        const float* P = smP + p * 6;
        const float* G = smG + g * 5;
        float tlx = fmaxf(P[0], G[0]);
        float tly = fmaxf(P[1], G[1]);
        float brx = fminf(P[2], G[2]);
        float bry = fminf(P[3], G[3]);
        float dx = fmaxf(brx - tlx, 0.f);
        float dy = fmaxf(bry - tly, 0.f);
        float inter = dx * dy * P[5];
        out[IOU_OFF + b * (NP_ * NGT_) + idx] = inter / (G[4] + P[4] - inter);
    }
}

// ---------------------------------------------------------------------------
// Kernel B: per image. Sum 4 partials + bias + leaky -> smHT [hw][op] stride 68
// (b128-aligned, conflict-free frags). GEMM2 via MFMA (wave w = m-tile w of 5),
// branchy epilogue stores. 320 threads = 5 waves.
// ---------------------------------------------------------------------------
__global__ __launch_bounds__(320) void gemm2_epilogue(
    const unsigned* __restrict__ wsp, const unsigned* __restrict__ gW2f,
    const float* __restrict__ B1, const float* __restrict__ B2,
    float* __restrict__ out)
{
    __shared__ __align__(16) unsigned smHT[49 * 68];   // 13,328 B

    const int tid  = threadIdx.x;
    const int b    = blockIdx.x;
    const int lane = tid & 63;
    const int w    = tid >> 6;         // 0..4 = m-tile
    const int quad = lane >> 4;
    const int m16  = lane & 15;

    // prefetch W2 A-frags (independent of phase 1)
    const uint4* Aw2 = (const uint4*)gW2f + w * 64 + lane;
    uint4 af0 = Aw2[0], af1 = Aw2[320], af2 = Aw2[640], af3 = Aw2[960];

    // ---- phase 1: sum partials, bias, leaky, pack -> smHT[hw*68+op] ----
    const unsigned* pb = wsp + b * 12544;
    for (int j = tid; j < 3136; j += 320) {
        int op = j / 49;
        int hw = j - op * 49;
        const unsigned* p = pb + op * 49 + hw;
        unsigned u0 = p[0], u1 = p[3136], u2 = p[6272], u3 = p[9408];
        float v0 = ((bflo(u0) + bflo(u1)) + (bflo(u2) + bflo(u3))) + B1[2 * op];
        float v1 = ((bfhi(u0) + bfhi(u1)) + (bfhi(u2) + bfhi(u3))) + B1[2 * op + 1];
        v0 = v0 > 0.f ? v0 : 0.01f * v0;
        v1 = v1 > 0.f ? v1 : 0.01f * v1;
        smHT[hw * 68 + op] = pack2bf(v0, v1);
    }
    __syncthreads();

    // ---- GEMM2 MFMA: C[o2][hw] = W2 @ h ----
    const int row3 = (m16 == 0) ? 48 : (m16 - 1);
    const unsigned* Bb[4] = {
        smHT + m16 * 68 + quad * 4,
        smHT + (16 + m16) * 68 + quad * 4,
        smHT + (32 + m16) * 68 + quad * 4,
        smHT + row3 * 68 + quad * 4
    };
    f32x4 acc[4];
    #pragma unroll
    for (int nt = 0; nt < 4; ++nt) acc[nt] = (f32x4)(0.f);
    uint4 afs[4] = { af0, af1, af2, af3 };
    #pragma unroll
    for (int ks2 = 0; ks2 < 4; ++ks2) {
        bf16x8 A = as_bf(afs[ks2]);
        const int co = ks2 * 16;
        #pragma unroll
        for (int nt = 0; nt < 4; ++nt) {
            bf16x8 Bf = ld_frag(Bb[nt] + co);
            acc[nt] = __builtin_amdgcn_mfma_f32_16x16x32_bf16(A, Bf, acc[nt], 0, 0, 0);
        }
    }

    // ---- epilogue ----
    #pragma unroll
    for (int nt = 0; nt < 4; ++nt) {
        int hw = (nt < 3) ? (nt * 16 + m16) : ((m16 == 0) ? 48 : -1);
        if (hw < 0) continue;
        #pragma unroll
        for (int r = 0; r < 4; ++r) {
            int o2 = w * 16 + quad * 4 + r;
            if (o2 >= OUTD_) continue;
            float a = acc[nt][r] + B2[o2];
            unsigned dst; float val;
            if (o2 < 36) {
                int an = o2 >> 2, kk = o2 & 3;
                val = (kk < 2) ? (sigmoidf_(a) - 0.5f) : a;
                dst = OFFS_OFF + b * 1764 + an * 196 + kk * 49 + hw;
            } else if (o2 < 45) {
                val = sigmoidf_(a);
                dst = CONF_OFF + b * 441 + (o2 - 36) * 49 + hw;
            } else {
                val = a;
                dst = CLS_OFF + b * 980 + (o2 - 45) * 49 + hw;
            }
            out[dst] = val;
        }
    }
}

// ---------------------------------------------------------------------------
// Mid fallback: R5 single fused kernel (proven), adapted to the new W1f layout:
// frag(mt=w, K32=2ch+ks) at uint4 index ch*1024 + ks*512 + w*64 + lane.
// ---------------------------------------------------------------------------
#define SF_STRIDE 644
__global__ __launch_bounds__(512) void fused_single(
    const float* __restrict__ F, const float* __restrict__ grid,
    const float* __restrict__ bbox, const float* __restrict__ anc,
    const unsigned* __restrict__ gW1f, const float* __restrict__ B1,
    const float* __restrict__ W2, const float* __restrict__ B2,
    float* __restrict__ out)
{
    __shared__ __align__(16) unsigned lds[49 * SF_STRIDE];
    unsigned* smF = lds;
    unsigned* smH = lds;
    float* smP = (float*)(lds + 3136);
    float* smG = (float*)(lds + 3136 + 2646);

    const int tid  = threadIdx.x;
    const int b    = blockIdx.x;
    const int lane = tid & 63;
    const int w    = tid >> 6;
    const int quad = lane >> 4;
    const int m16  = lane & 15;
    const float* Fb = F + b * (CIN_ * HW_);

    for (int i = tid; i < 640 * 49; i += 512) {
        int cp = i / 49;
        int hw = i - cp * 49;
        const float* s = Fb + (2 * cp) * HW_ + hw;
        smF[hw * SF_STRIDE + cp] = pack2bf(s[0], s[HW_]);
    }
    __syncthreads();

    const int row3 = (m16 == 0) ? 48 : (m16 - 1);
    const unsigned* Bb[4] = {
        smF + m16 * SF_STRIDE + quad * 4,
        smF + (16 + m16) * SF_STRIDE + quad * 4,
        smF + (32 + m16) * SF_STRIDE + quad * 4,
        smF + row3 * SF_STRIDE + quad * 4
    };
    const uint4* Aw = (const uint4*)gW1f + w * 64 + lane;

    f32x4 acc[4];
    #pragma unroll
    for (int nt = 0; nt < 4; ++nt) acc[nt] = (f32x4)(0.f);

    uint4 a0 = Aw[0], a1 = Aw[512];
    for (int ch = 0; ch < 20; ++ch) {
        uint4 n0, n1;
        if (ch < 19) { n0 = Aw[(ch + 1) * 1024]; n1 = Aw[(ch + 1) * 1024 + 512]; }
        const int coff = ch * 32;
        bf16x8 A0 = as_bf(a0), A1 = as_bf(a1);
        #pragma unroll
        for (int nt = 0; nt < 4; ++nt) {
            bf16x8 b0 = ld_frag(Bb[nt] + coff);
            bf16x8 b1 = ld_frag(Bb[nt] + coff + 16);
            acc[nt] = __builtin_amdgcn_mfma_f32_16x16x32_bf16(A0, b0, acc[nt], 0, 0, 0);
            acc[nt] = __builtin_amdgcn_mfma_f32_16x16x32_bf16(A1, b1, acc[nt], 0, 0, 0);
        }
        a0 = n0; a1 = n1;
    }
    __syncthreads();

    #pragma unroll
    for (int nt = 0; nt < 4; ++nt) {
        int hw = (nt < 3) ? (nt * 16 + m16) : ((m16 == 0) ? 48 : -1);
        if (hw >= 0) {
            #pragma unroll
            for (int rp = 0; rp < 2; ++rp) {
                int o0 = w * 16 + quad * 4 + 2 * rp;
                float v0 = acc[nt][2 * rp]     + B1[o0];
                float v1 = acc[nt][2 * rp + 1] + B1[o0 + 1];
                v0 = v0 > 0.f ? v0 : 0.01f * v0;
                v1 = v1 > 0.f ? v1 : 0.01f * v1;
                smH[(o0 >> 1) * HW_ + hw] = pack2bf(v0, v1);
            }
        }
    }
    if (tid < NP_) {
        int pp = tid, a = pp / 49, r = pp - a * 49;
        float cx = grid[b * 98 + 2 * r], cy = grid[b * 98 + 2 * r + 1];
        float hx = anc[2 * a] * 0.5f,    hy = anc[2 * a + 1] * 0.5f;
        float x1 = cx - hx, y1 = cy - hy, x2 = cx + hx, y2 = cy + hy;
        smP[pp * 6 + 0] = x1; smP[pp * 6 + 1] = y1;
        smP[pp * 6 + 2] = x2; smP[pp * 6 + 3] = y2;
        smP[pp * 6 + 4] = (x2 - x1) * (y2 - y1);
        smP[pp * 6 + 5] = (fminf(fminf(x1, y1), fminf(x2, y2)) > 0.f) ? 1.f : 0.f;
    }
    if (tid >= 472) {
        int g = tid - 472;
        float x1 = bbox[b * 200 + g * 5 + 0];
        float y1 = bbox[b * 200 + g * 5 + 1];
        float x2 = bbox[b * 200 + g * 5 + 2];
        float y2 = bbox[b * 200 + g * 5 + 3];
        smG[g * 5 + 0] = x1; smG[g * 5 + 1] = y1;
        smG[g * 5 + 2] = x2; smG[g * 5 + 3] = y2;
        smG[g * 5 + 4] = (x2 - x1) * (y2 - y1);
    }
    __syncthreads();

    for (int idx = tid; idx < OUTD_ * HW_; idx += 512) {
        int o2 = idx / 49;
        int hw = idx - o2 * 49;
        const float2* wr = (const float2*)(W2 + o2 * HID_);
        float s0 = 0.f, s1 = 0.f;
        #pragma unroll 8
        for (int k2 = 0; k2 < 64; ++k2) {
            unsigned hp = smH[k2 * HW_ + hw];
            float2 wv = wr[k2];
            s0 = fmaf(wv.x, bflo(hp), s0);
            s1 = fmaf(wv.y, bfhi(hp), s1);
        }
        float a = B2[o2] + (s0 + s1);
        unsigned dst; float val;
        if (o2 < 36) {
            int an = o2 >> 2, kk = o2 & 3;
            val = (kk < 2) ? (sigmoidf_(a) - 0.5f) : a;
            dst = OFFS_OFF + b * 1764 + an * 196 + kk * 49 + hw;
        } else if (o2 < 45) {
            val = sigmoidf_(a);
            dst = CONF_OFF + b * 441 + (o2 - 36) * 49 + hw;
        } else {
            val = a;
            dst = CLS_OFF + b * 980 + (o2 - 45) * 49 + hw;
        }
        out[dst] = val;
    }
    for (int idx = tid; idx < NP_ * NGT_; idx += 512) {
        int pp = idx / 40;
        int g  = idx - pp * 40;
        const float* P = smP + pp * 6;
        const float* G = smG + g * 5;
        float tlx = fmaxf(P[0], G[0]);
        float tly = fmaxf(P[1], G[1]);
        float brx = fminf(P[2], G[2]);
        float bry = fminf(P[3], G[3]);
        float dx = fmaxf(brx - tlx, 0.f);
        float dy = fmaxf(bry - tly, 0.f);
        float inter = dx * dy * P[5];
        out[IOU_OFF + b * (NP_ * NGT_) + idx] = inter / (G[4] + P[4] - inter);
    }
}

// ---------------------------------------------------------------------------
// No-ws fallback (R3 structure, proven).
// ---------------------------------------------------------------------------
__global__ __launch_bounds__(512) void fused_fallback(
    const float* __restrict__ F, const float* __restrict__ grid,
    const float* __restrict__ bbox, const float* __restrict__ anc,
    const float* __restrict__ W1, const float* __restrict__ B1,
    const float* __restrict__ W2, const float* __restrict__ B2,
    float* __restrict__ out)
{
    __shared__ __align__(16) unsigned lds[4608 + 2304 + 6272];
    unsigned* smA = lds;
    unsigned* smB = lds + 4608;
    float*    smH = (float*)(lds + 4608 + 2304);
    float* smP = (float*)lds;
    float* smG = (float*)(lds + 4608);

    const int tid  = threadIdx.x;
    const int b    = blockIdx.x;
    const int lane = tid & 63;
    const int w    = tid >> 6;
    const int quad = lane >> 4;
    const int m16  = lane & 15;
    const float* Fb = F + b * (CIN_ * HW_);

    f32x4 acc[4];
    #pragma unroll
    for (int nt = 0; nt < 4; ++nt) acc[nt] = (f32x4)(0.f);

    for (int ch = 0; ch < 20; ++ch) {
        const int c0 = ch * 64;
        __syncthreads();
        #pragma unroll
        for (int rr = 0; rr < 8; ++rr) {
            int pi = tid + rr * 512;
            int o = pi >> 5, cp = pi & 31;
            float2 fx = *(const float2*)(W1 + o * CIN_ + c0 + 2 * cp);
            smA[o * 36 + cp] = pack2bf(fx.x, fx.y);
        }
        for (int pi = tid; pi < 32 * 49; pi += 512) {
            int cp = pi / 49;
            int hw = pi - cp * 49;
            const float* src = Fb + (c0 + 2 * cp) * HW_ + hw;
            smB[hw * 36 + cp] = pack2bf(src[0], src[HW_]);
        }
        __syncthreads();
        const unsigned* Ab = smA + (w * 16 + m16) * 36 + quad * 4;
        const unsigned* Bb = smB + m16 * 36 + quad * 4;
        #pragma unroll
        for (int ks = 0; ks < 2; ++ks) {
            bf16x8 af = ld_frag(Ab + ks * 16);
            #pragma unroll
            for (int nt = 0; nt < 4; ++nt) {
                bf16x8 bf = ld_frag(Bb + nt * 16 * 36 + ks * 16);
                acc[nt] = __builtin_amdgcn_mfma_f32_16x16x32_bf16(af, bf, acc[nt], 0, 0, 0);
            }
        }
    }
    #pragma unroll
    for (int nt = 0; nt < 4; ++nt) {
        int hw = nt * 16 + m16;
        if (hw < HW_) {
            #pragma unroll
            for (int r = 0; r < 4; ++r) {
                int o = w * 16 + quad * 4 + r;
                float v = acc[nt][r] + B1[o];
                v = v > 0.f ? v : 0.01f * v;
                smH[o * HW_ + hw] = v;
            }
        }
    }
    __syncthreads();
    if (tid < NP_) {
        int pp = tid, a = pp / 49, r = pp - a * 49;
        float cx = grid[b * 98 + 2 * r], cy = grid[b * 98 + 2 * r + 1];
        float hx = anc[2 * a] * 0.5f,    hy = anc[2 * a + 1] * 0.5f;
        float x1 = cx - hx, y1 = cy - hy, x2 = cx + hx, y2 = cy + hy;
        smP[pp * 6 + 0] = x1; smP[pp * 6 + 1] = y1;
        smP[pp * 6 + 2] = x2; smP[pp * 6 + 3] = y2;
        smP[pp * 6 + 4] = (x2 - x1) * (y2 - y1);
        smP[pp * 6 + 5] = (fminf(fminf(x1, y1), fminf(x2, y2)) > 0.f) ? 1.f : 0.f;
    }
    if (tid >= 472) {
        int g = tid - 472;
        float x1 = bbox[b * 200 + g * 5 + 0];
        float y1 = bbox[b * 200 + g * 5 + 1];
        float x2 = bbox[b * 200 + g * 5 + 2];
        float y2 = bbox[b * 200 + g * 5 + 3];
        smG[g * 5 + 0] = x1; smG[g * 5 + 1] = y1;
        smG[g * 5 + 2] = x2; smG[g * 5 + 3] = y2;
        smG[g * 5 + 4] = (x2 - x1) * (y2 - y1);
    }
    for (int idx = tid; idx < OUTD_ * HW_; idx += 512) {
        int o2 = idx / 49;
        int hw = idx - o2 * 49;
        const float4* wr = (const float4*)(W2 + o2 * HID_);
        const float*  hc = smH + hw;
        float s0 = 0.f, s1 = 0.f, s2 = 0.f, s3 = 0.f;
        #pragma unroll 8
        for (int k4 = 0; k4 < 32; ++k4) {
            float4 wv = wr[k4];
            s0 = fmaf(wv.x, hc[(4 * k4 + 0) * HW_], s0);
            s1 = fmaf(wv.y, hc[(4 * k4 + 1) * HW_], s1);
            s2 = fmaf(wv.z, hc[(4 * k4 + 2) * HW_], s2);
            s3 = fmaf(wv.w, hc[(4 * k4 + 3) * HW_], s3);
        }
        float a = B2[o2] + ((s0 + s1) + (s2 + s3));
        unsigned dst; float val;
        if (o2 < 36) { int an = o2 >> 2, kk = o2 & 3;
            val = (kk < 2) ? (sigmoidf_(a) - 0.5f) : a;
            dst = OFFS_OFF + b * 1764 + an * 196 + kk * 49 + hw;
        } else if (o2 < 45) { val = sigmoidf_(a);
            dst = CONF_OFF + b * 441 + (o2 - 36) * 49 + hw;
        } else { val = a;
            dst = CLS_OFF + b * 980 + (o2 - 45) * 49 + hw; }
        out[dst] = val;
    }
    __syncthreads();
    for (int idx = tid; idx < NP_ * NGT_; idx += 512) {
        int pp = idx / 40;
        int g  = idx - pp * 40;
        const float* P = smP + pp * 6;
        const float* G = smG + g * 5;
        float tlx = fmaxf(P[0], G[0]);
        float tly = fmaxf(P[1], G[1]);
        float brx = fminf(P[2], G[2]);
        float bry = fminf(P[3], G[3]);
        float dx = fmaxf(brx - tlx, 0.f);
        float dy = fmaxf(bry - tly, 0.f);
        float inter = dx * dy * P[5];
        out[IOU_OFF + b * (NP_ * NGT_) + idx] = inter / (G[4] + P[4] - inter);
    }
}

extern "C" void kernel_launch(void* const* d_in, const int* in_sizes, int n_in,
                              void* d_out, int out_size, void* d_ws, size_t ws_size,
                              hipStream_t stream) {
    const float* F  = (const float*)d_in[0];
    const float* G  = (const float*)d_in[1];
    const float* BB = (const float*)d_in[2];
    const float* AN = (const float*)d_in[3];
    const float* W1 = (const float*)d_in[4];
    const float* B1 = (const float*)d_in[5];
    const float* W2 = (const float*)d_in[6];
    const float* B2 = (const float*)d_in[7];
    float* out = (float*)d_out;
    unsigned* wsu = (unsigned*)d_ws;

    if (ws_size >= (size_t)WS_NEED_FULL) {
        prep_w1f<<<320, 256, 0, stream>>>(W1, wsu + WS_W1F);
        prep_w2f<<<20, 256, 0, stream>>>(W2, wsu + WS_W2F);
        gemm1_partial<<<1024, 256, 0, stream>>>(F, G, BB, AN, wsu + WS_W1F,
                                                wsu + WS_PART, out);
        gemm2_epilogue<<<256, 320, 0, stream>>>(wsu + WS_PART, wsu + WS_W2F,
                                                B1, B2, out);
    } else if (ws_size >= (size_t)WS_NEED_MID) {
        prep_w1f<<<320, 256, 0, stream>>>(W1, wsu + WS_W1F);
        fused_single<<<256, 512, 0, stream>>>(F, G, BB, AN, wsu + WS_W1F,
                                              B1, W2, B2, out);
    } else {
        fused_fallback<<<256, 512, 0, stream>>>(F, G, BB, AN, W1, B1, W2, B2, out);
    }
}